// Round 19
// baseline (131.697 us; speedup 1.0000x reference)
//
#include <hip/hip_runtime.h>
#include <hip/hip_bf16.h>
#include <stdint.h>

// B=2, T=2048, C=1024, H=16, D=64
// out = ( causal_attn(x@Wqkv) ) @ Wout
// bf16 MFMA pipeline, f32 accumulate everywhere.
// R19: stabilization — R17 verbatim (session best, 131.3us).
//  - prep_fused: x-cast + both weight transposes in one launch.
//  - gemm128: 128^2/BK=32, triple-buffered, depth-2 counted-vmcnt (R7).
//  - flash: R15 complementary static mapping (512 blocks x 8 waves, 2/CU,
//    34 tiles per CU exactly), pairing-structure body (REQUIRED: straight-
//    line staged bodies miscompile — R10/R18 evidence), TBAA-typed lP.
// Known plateaus: qkv 59.5us (5 schedule variants), flash ~46-49us,
// out-proj 16us, prep ~6us (BW floor).

#define Bv 2
#define Tv 2048
#define Cv 1024
#define Hv 16
#define Dv 64
#define Mv 4096  // B*T

typedef __attribute__((ext_vector_type(8))) __bf16 bf16x8;
typedef __attribute__((ext_vector_type(4))) __bf16 bf16x4;
typedef __attribute__((ext_vector_type(4))) float f32x4;
typedef __attribute__((ext_vector_type(4))) unsigned short ushort4v;

__device__ __forceinline__ unsigned short f2bs(float f) {
  union { __bf16 h; unsigned short s; } u;
  u.h = (__bf16)f;  // native HW cvt (RNE on gfx950)
  return u.s;
}

__device__ __forceinline__ void gload16(const void* g, void* l) {
  __builtin_amdgcn_global_load_lds(
      (__attribute__((address_space(1))) void*)(uintptr_t)g,
      (__attribute__((address_space(3))) void*)(unsigned int)(uintptr_t)l,
      16, 0, 0);
}

__device__ __forceinline__ bf16x8 ldfrag(const unsigned short* p) {
  return *reinterpret_cast<const bf16x8*>(p);
}
__device__ __forceinline__ bf16x8 ldfragb(const __bf16* p) {
  return *reinterpret_cast<const bf16x8*>(p);
}

// ---------------- fused prep: x cast + w_qkv transpose + w_out transpose ---
// blocks [0,2048): cast x f32->bf16, 8 elems/thread.
// blocks [2048,5120): transpose+cast w_qkv [1024][3072] -> wqkvT [3072][1024]
// blocks [5120,6144): transpose+cast w_out [1024][1024] -> woutT [1024][1024]
__global__ void __launch_bounds__(256) prep_fused(
    const float* __restrict__ x, unsigned short* __restrict__ xb,
    const float* __restrict__ w_qkv, unsigned short* __restrict__ wqkvT,
    const float* __restrict__ w_out, unsigned short* __restrict__ woutT) {
  __shared__ float tile[32][33];
  int idx = blockIdx.x;
  if (idx < 2048) {  // cast role
    int i = (idx * 256 + threadIdx.x) * 8;
    float4 a = *reinterpret_cast<const float4*>(x + i);
    float4 b = *reinterpret_cast<const float4*>(x + i + 4);
    ushort4v o0, o1;
    o0.x = f2bs(a.x); o0.y = f2bs(a.y); o0.z = f2bs(a.z); o0.w = f2bs(a.w);
    o1.x = f2bs(b.x); o1.y = f2bs(b.y); o1.z = f2bs(b.z); o1.w = f2bs(b.w);
    *reinterpret_cast<ushort4v*>(xb + i) = o0;
    *reinterpret_cast<ushort4v*>(xb + i + 4) = o1;
    return;
  }
  // transpose roles: in f32 [1024][Cc] -> out bf16 [Cc][1024]
  const float* in;
  unsigned short* out;
  int Cc, bx, by;
  if (idx < 5120) {
    int t = idx - 2048;
    in = w_qkv; out = wqkvT; Cc = 3072; bx = t % 96; by = t / 96;
  } else {
    int t = idx - 5120;
    in = w_out; out = woutT; Cc = 1024; bx = t & 31; by = t >> 5;
  }
  const int R = 1024;
  int c0 = bx * 32, r0 = by * 32;
  int tc = threadIdx.x & 31, tr = threadIdx.x >> 5;
#pragma unroll
  for (int i = 0; i < 4; i++)
    tile[tr + i * 8][tc] = in[(size_t)(r0 + tr + i * 8) * Cc + c0 + tc];
  __syncthreads();
#pragma unroll
  for (int i = 0; i < 4; i++)
    out[(size_t)(c0 + tr + i * 8) * R + r0 + tc] = f2bs(tile[tc][tr + i * 8]);
}

// ---------------- GEMM: C[M][N] = A[M][1024] * Bt[N][1024]^T ----------------
// 128x128 tile, BK=32, 256 threads (2x2 waves, each 64x64 = 4x4 MFMA frags).
// Triple-buffered LDS (48KB), depth-2 counted-vmcnt pipeline (R7, best).
template <int EPI>
__global__ void __launch_bounds__(256) gemm128(
    const unsigned short* __restrict__ A, const unsigned short* __restrict__ Bt,
    float* __restrict__ outF, unsigned short* __restrict__ qo,
    unsigned short* __restrict__ ko, unsigned short* __restrict__ vTo, int N) {
  __shared__ unsigned short la[3][4][128][8];
  __shared__ unsigned short lb[3][4][128][8];
  const int K = 1024;
  const int NT = K / 32;  // 32 K-tiles
  int mb = blockIdx.y * 128, nb = blockIdx.x * 128;
  int tid = threadIdx.x;
  int l = tid & 63, w = tid >> 6;
  int wr = w >> 1, wc = w & 1;
  int lr = l & 15, lg = l >> 4;
  f32x4 acc[4][4] = {};
  int c0 = tid >> 7, r0 = tid & 127;

  auto STAGE = [&](int t, int buf) {
    int kb = t * 32;
    gload16(A + (size_t)(mb + r0) * K + kb + c0 * 8, &la[buf][c0][r0][0]);
    gload16(A + (size_t)(mb + r0) * K + kb + (c0 + 2) * 8, &la[buf][c0 + 2][r0][0]);
    gload16(Bt + (size_t)(nb + r0) * K + kb + c0 * 8, &lb[buf][c0][r0][0]);
    gload16(Bt + (size_t)(nb + r0) * K + kb + (c0 + 2) * 8, &lb[buf][c0 + 2][r0][0]);
  };
  auto COMPUTE = [&](int buf) {
    bf16x8 af[4], bfr[4];
#pragma unroll
    for (int mi = 0; mi < 4; mi++) af[mi] = ldfrag(&la[buf][lg][wr * 64 + mi * 16 + lr][0]);
#pragma unroll
    for (int ni = 0; ni < 4; ni++) bfr[ni] = ldfrag(&lb[buf][lg][wc * 64 + ni * 16 + lr][0]);
#pragma unroll
    for (int mi = 0; mi < 4; mi++)
#pragma unroll
      for (int ni = 0; ni < 4; ni++)
        acc[mi][ni] = __builtin_amdgcn_mfma_f32_16x16x32_bf16(af[mi], bfr[ni], acc[mi][ni], 0, 0, 0);
  };

  STAGE(0, 0);
  STAGE(1, 1);
  for (int i = 0; i < NT - 1; ++i) {
    asm volatile("s_waitcnt vmcnt(4)" ::: "memory");
    __builtin_amdgcn_s_barrier();
    __builtin_amdgcn_sched_barrier(0);
    if (i + 2 < NT) STAGE(i + 2, (i + 2) % 3);
    COMPUTE(i % 3);
  }
  asm volatile("s_waitcnt vmcnt(0)" ::: "memory");
  __builtin_amdgcn_s_barrier();
  __builtin_amdgcn_sched_barrier(0);
  COMPUTE((NT - 1) % 3);

#pragma unroll
  for (int mi = 0; mi < 4; mi++) {
#pragma unroll
    for (int ni = 0; ni < 4; ni++) {
      int row0 = mb + wr * 64 + mi * 16 + lg * 4;
      int col = nb + wc * 64 + ni * 16 + lr;
      if (EPI == 1) {
#pragma unroll
        for (int r = 0; r < 4; r++)
          outF[(size_t)(row0 + r) * N + col] = acc[mi][ni][r];
      } else {
        int which = col >> 10, cc = col & 1023;
        int h = cc >> 6, d = cc & 63;
        int bb = row0 >> 11, t = row0 & 2047;
        size_t bh = (size_t)bb * Hv + h;
        if (which == 0) {
#pragma unroll
          for (int r = 0; r < 4; r++)
            qo[(bh * Tv + t + r) * Dv + d] = f2bs(acc[mi][ni][r]);
        } else if (which == 1) {
#pragma unroll
          for (int r = 0; r < 4; r++)
            ko[(bh * Tv + t + r) * Dv + d] = f2bs(acc[mi][ni][r]);
        } else {  // v stored transposed [B,H,D,T]
          ushort4v pk;
#pragma unroll
          for (int r = 0; r < 4; r++) pk[r] = f2bs(acc[mi][ni][r]);
          *reinterpret_cast<ushort4v*>(&vTo[(bh * Dv + d) * Tv + t]) = pk;
        }
      }
    }
  }
}

// ---------------- flash attention (R15: complementary static mapping) ------
// grid 512 blocks (1D), 512 threads = 8 waves; block covers 128 q-rows.
// p = idx&255, head = p&31, qh = 8+(p>>5); idx<256 -> qblk=qh (heavy),
// idx>=256 -> qblk=15-qh (light). Co-resident pair (c, c+256) sums to 34
// tiles on every CU. KT=64, dbuf K/V, one __syncthreads per tile. Per-wave
// causal mask/skip. Swapped QK^T; bf16-typed packed P-stores; ones-MFMA
// row-sum; defer-max. NOTE: the staged body must stay in this proven
// structure — straight-line single-tile variants miscompile (R10/R18).
__global__ void __launch_bounds__(512) flash_attn(
    const unsigned short* __restrict__ Q, const unsigned short* __restrict__ Kk,
    const unsigned short* __restrict__ Vt, unsigned short* __restrict__ O) {
  __shared__ unsigned short lK[2][8][64][8];  // 16KB
  __shared__ unsigned short lV[2][8][64][8];  // 16KB
  __shared__ __bf16 lP[8][16][72];            // 18KB, wave-private slabs
  int idx = blockIdx.x;
  int p = idx & 255;
  int bh = p & 31;
  int qh = 8 + (p >> 5);
  int qblk = (idx < 256) ? qh : (15 - qh);
  int b = bh >> 4, h = bh & 15;
  int tid = threadIdx.x;
  int l = tid & 63, w = tid >> 6;  // w = 0..7
  int lr = l & 15, lg = l >> 4;
  const unsigned short* Qp = Q + (size_t)bh * Tv * Dv;
  const unsigned short* Kp = Kk + (size_t)bh * Tv * Dv;
  const unsigned short* Vp = Vt + (size_t)bh * Dv * Tv;
  const float Cs = 0.125f * 1.4426950408889634f;  // scale * log2(e)
  const float THRraw = 8.0f / Cs;                 // defer-max threshold (P <= 2^8)
  const __bf16 kOne = (__bf16)1.0f;
  const bf16x8 vone = {kOne, kOne, kOne, kOne, kOne, kOne, kOne, kOne};
  int sr = l, sc = w;  // staging: wave w stages chunk w (1 K + 1 V gload16)

  int q0 = qblk * 128;
  int nt = 2 * qblk + 2;
  int qrow = q0 + w * 16 + lr;
  bf16x8 qf0 = ldfrag(&Qp[(size_t)qrow * Dv + lg * 8]);
  bf16x8 qf1 = ldfrag(&Qp[(size_t)qrow * Dv + 32 + lg * 8]);
  f32x4 o[4] = {};
  f32x4 lsum = {0.f, 0.f, 0.f, 0.f};  // rho-domain (row = lg*4+r)
  float mrow = -1e30f;                // lr-domain scalar (row = lr)
  int wlo = q0 + w * 16;              // wave's lowest q-row

  auto STAGE = [&](int it, int buf) {
    int k0 = it * 64;
    gload16(Kp + (size_t)(k0 + sr) * Dv + sc * 8, &lK[buf][sc][sr][0]);
    gload16(Vp + (size_t)sr * Tv + k0 + sc * 8, &lV[buf][sc][sr][0]);
  };

  STAGE(0, 0);
  int cur = 0;
  for (int it = 0; it < nt; ++it) {
    __syncthreads();  // drains prefetch of tile `it` + protects buffer reuse
    if (it + 1 < nt) STAGE(it + 1, cur ^ 1);
    int k0 = it * 64;
    if (k0 <= wlo + 15) {  // wave-uniform skip: tile intersects wave's rows
      // S^T = K Q^T : 4 row blocks of 16 keys; col=lr is the q-row.
      f32x4 s[4] = {};
#pragma unroll
      for (int j = 0; j < 4; ++j) {
        bf16x8 kf0 = ldfrag(&lK[cur][lg][j * 16 + lr][0]);
        s[j] = __builtin_amdgcn_mfma_f32_16x16x32_bf16(kf0, qf0, s[j], 0, 0, 0);
        bf16x8 kf1 = ldfrag(&lK[cur][4 + lg][j * 16 + lr][0]);
        s[j] = __builtin_amdgcn_mfma_f32_16x16x32_bf16(kf1, qf1, s[j], 0, 0, 0);
      }
      // lane (lg,lr) holds keys {k0+16j+4lg+r} for q-row lr
      int qg = wlo + lr;
      if (k0 + 63 > wlo) {  // diagonal straddle for this wave
#pragma unroll
        for (int j = 0; j < 4; ++j)
#pragma unroll
          for (int r = 0; r < 4; ++r)
            if (k0 + j * 16 + lg * 4 + r > qg) s[j][r] = -1e30f;
      }
      // tile max of q-row lr: 15 local fmax + 2 shuffles across lg
      float v = fmaxf(fmaxf(fmaxf(s[0][0], s[0][1]), fmaxf(s[0][2], s[0][3])),
                      fmaxf(fmaxf(s[1][0], s[1][1]), fmaxf(s[1][2], s[1][3])));
      v = fmaxf(v, fmaxf(fmaxf(fmaxf(s[2][0], s[2][1]), fmaxf(s[2][2], s[2][3])),
                         fmaxf(fmaxf(s[3][0], s[3][1]), fmaxf(s[3][2], s[3][3]))));
      v = fmaxf(v, __shfl_xor(v, 16));
      v = fmaxf(v, __shfl_xor(v, 32));
      // T13 defer-max: rescale only when this row's max grew past threshold
      if (__any(v > mrow + THRraw)) {
        float mn = fmaxf(mrow, v);
        float al = exp2f((mrow - mn) * Cs);  // lr-domain
        mrow = mn;
#pragma unroll
        for (int r = 0; r < 4; ++r) {  // cross to rho-domain (4 shfl, rare)
          float alr = __shfl(al, (l & 48) | (lg * 4 + r));
          lsum[r] *= alr;
#pragma unroll
          for (int nb = 0; nb < 4; ++nb) o[nb][r] *= alr;
        }
      }
      // P = exp2((S - m)*Cs), packed 4 consecutive keys -> one ds_write_b64
#pragma unroll
      for (int j = 0; j < 4; ++j) {
        bf16x4 pk;
#pragma unroll
        for (int r = 0; r < 4; ++r) pk[r] = (__bf16)exp2f((s[j][r] - mrow) * Cs);
        *reinterpret_cast<bf16x4*>(&lP[w][lr][j * 16 + lg * 4]) = pk;
      }
      asm volatile("" ::: "memory");  // fence: P stores before P reads
      // PV + row-sum: A = P (wave-private LDS), B = V^T tile / ones
      f32x4 srow = {0.f, 0.f, 0.f, 0.f};
#pragma unroll
      for (int kk = 0; kk < 2; ++kk) {
        bf16x8 pf = ldfragb(&lP[w][lr][kk * 32 + lg * 8]);
        srow = __builtin_amdgcn_mfma_f32_16x16x32_bf16(pf, vone, srow, 0, 0, 0);
#pragma unroll
        for (int nb = 0; nb < 4; ++nb) {
          bf16x8 vf = ldfrag(&lV[cur][kk * 4 + lg][nb * 16 + lr][0]);
          o[nb] = __builtin_amdgcn_mfma_f32_16x16x32_bf16(pf, vf, o[nb], 0, 0, 0);
        }
      }
      asm volatile("" ::: "memory");  // fence: P reads before next stores
#pragma unroll
      for (int r = 0; r < 4; ++r) lsum[r] += srow[r];
    }
    cur ^= 1;
  }
  // epilogue: normalize, write [B,T,H*D] bf16 (rho-domain rows)
#pragma unroll
  for (int r = 0; r < 4; ++r) {
    int t = q0 + w * 16 + lg * 4 + r;
    float inv = 1.0f / lsum[r];
    size_t rowbase = ((size_t)b * Tv + t) * Cv + h * Dv;
#pragma unroll
    for (int nb = 0; nb < 4; ++nb)
      O[rowbase + nb * 16 + lr] = f2bs(o[nb][r] * inv);
  }
}

// ---------------- host ----------------
extern "C" void kernel_launch(void* const* d_in, const int* in_sizes, int n_in,
                              void* d_out, int out_size, void* d_ws, size_t ws_size,
                              hipStream_t stream) {
  const float* x = (const float*)d_in[0];      // [2,2048,1024]
  const float* w_qkv = (const float*)d_in[1];  // [1024,3072]
  const float* w_out = (const float*)d_in[2];  // [1024,1024]
  float* out = (float*)d_out;                  // [2,2048,1024] f32
  char* ws = (char*)d_ws;
  const size_t MB = 1u << 20;
  unsigned short* xb    = (unsigned short*)(ws + 0);        // 8MB  [4096][1024]
  unsigned short* wqkvT = (unsigned short*)(ws + 8 * MB);   // 6MB  [3072][1024]
  unsigned short* woutT = (unsigned short*)(ws + 14 * MB);  // 2MB  [1024][1024]
  unsigned short* qb    = (unsigned short*)(ws + 16 * MB);  // 8MB  [B,H,T,D]
  unsigned short* kb    = (unsigned short*)(ws + 24 * MB);  // 8MB  [B,H,T,D]
  unsigned short* vTb   = (unsigned short*)(ws + 32 * MB);  // 8MB  [B,H,D,T]
  unsigned short* ab    = (unsigned short*)(ws + 40 * MB);  // 8MB  [4096][1024]

  prep_fused<<<dim3(2048 + 3072 + 1024), dim3(256), 0, stream>>>(
      x, xb, w_qkv, wqkvT, w_out, woutT);
  gemm128<0><<<dim3(3072 / 128, Mv / 128), dim3(256), 0, stream>>>(
      xb, wqkvT, nullptr, qb, kb, vTb, 3072);
  flash_attn<<<dim3(512), dim3(512), 0, stream>>>(qb, kb, vTb, ab);
  gemm128<1><<<dim3(Cv / 128, Mv / 128), dim3(256), 0, stream>>>(
      ab, woutT, out, nullptr, nullptr, nullptr, Cv);
}

// Round 20
// 129.493 us; speedup vs baseline: 1.0170x; 1.0170x over previous
//
#include <hip/hip_runtime.h>
#include <hip/hip_bf16.h>
#include <stdint.h>

// B=2, T=2048, C=1024, H=16, D=64
// out = ( causal_attn(x@Wqkv) ) @ Wout
// bf16 MFMA pipeline, f32 accumulate everywhere.
// R20: R19 + XCD-rectangle swizzle in gemm128: XCD = orig%8 (HW round-robin);
// each XCD gets a (gx/2)x(gy/4) RECTANGLE of output tiles -> per-XCD L2
// working set ~5MB (qkv) / ~3MB (out-proj), vs R6's failed stripes that
// spanned all of B (6MB > 4MB L2). Mechanism: depth-2 vmcnt covers L2-hit
// latency (~200cy) but not HBM-miss (~900cy); raising hit rate shrinks the
// barrier-drain stall. Bijective, deterministic, math unchanged.
// prep_fused / flash byte-identical to R19.

#define Bv 2
#define Tv 2048
#define Cv 1024
#define Hv 16
#define Dv 64
#define Mv 4096  // B*T

typedef __attribute__((ext_vector_type(8))) __bf16 bf16x8;
typedef __attribute__((ext_vector_type(4))) __bf16 bf16x4;
typedef __attribute__((ext_vector_type(4))) float f32x4;
typedef __attribute__((ext_vector_type(4))) unsigned short ushort4v;

__device__ __forceinline__ unsigned short f2bs(float f) {
  union { __bf16 h; unsigned short s; } u;
  u.h = (__bf16)f;  // native HW cvt (RNE on gfx950)
  return u.s;
}

__device__ __forceinline__ void gload16(const void* g, void* l) {
  __builtin_amdgcn_global_load_lds(
      (__attribute__((address_space(1))) void*)(uintptr_t)g,
      (__attribute__((address_space(3))) void*)(unsigned int)(uintptr_t)l,
      16, 0, 0);
}

__device__ __forceinline__ bf16x8 ldfrag(const unsigned short* p) {
  return *reinterpret_cast<const bf16x8*>(p);
}
__device__ __forceinline__ bf16x8 ldfragb(const __bf16* p) {
  return *reinterpret_cast<const bf16x8*>(p);
}

// ---------------- fused prep: x cast + w_qkv transpose + w_out transpose ---
// blocks [0,2048): cast x f32->bf16, 8 elems/thread.
// blocks [2048,5120): transpose+cast w_qkv [1024][3072] -> wqkvT [3072][1024]
// blocks [5120,6144): transpose+cast w_out [1024][1024] -> woutT [1024][1024]
__global__ void __launch_bounds__(256) prep_fused(
    const float* __restrict__ x, unsigned short* __restrict__ xb,
    const float* __restrict__ w_qkv, unsigned short* __restrict__ wqkvT,
    const float* __restrict__ w_out, unsigned short* __restrict__ woutT) {
  __shared__ float tile[32][33];
  int idx = blockIdx.x;
  if (idx < 2048) {  // cast role
    int i = (idx * 256 + threadIdx.x) * 8;
    float4 a = *reinterpret_cast<const float4*>(x + i);
    float4 b = *reinterpret_cast<const float4*>(x + i + 4);
    ushort4v o0, o1;
    o0.x = f2bs(a.x); o0.y = f2bs(a.y); o0.z = f2bs(a.z); o0.w = f2bs(a.w);
    o1.x = f2bs(b.x); o1.y = f2bs(b.y); o1.z = f2bs(b.z); o1.w = f2bs(b.w);
    *reinterpret_cast<ushort4v*>(xb + i) = o0;
    *reinterpret_cast<ushort4v*>(xb + i + 4) = o1;
    return;
  }
  // transpose roles: in f32 [1024][Cc] -> out bf16 [Cc][1024]
  const float* in;
  unsigned short* out;
  int Cc, bx, by;
  if (idx < 5120) {
    int t = idx - 2048;
    in = w_qkv; out = wqkvT; Cc = 3072; bx = t % 96; by = t / 96;
  } else {
    int t = idx - 5120;
    in = w_out; out = woutT; Cc = 1024; bx = t & 31; by = t >> 5;
  }
  const int R = 1024;
  int c0 = bx * 32, r0 = by * 32;
  int tc = threadIdx.x & 31, tr = threadIdx.x >> 5;
#pragma unroll
  for (int i = 0; i < 4; i++)
    tile[tr + i * 8][tc] = in[(size_t)(r0 + tr + i * 8) * Cc + c0 + tc];
  __syncthreads();
#pragma unroll
  for (int i = 0; i < 4; i++)
    out[(size_t)(c0 + tr + i * 8) * R + r0 + tc] = f2bs(tile[tc][tr + i * 8]);
}

// ---------------- GEMM: C[M][N] = A[M][1024] * Bt[N][1024]^T ----------------
// 128x128 tile, BK=32, 256 threads (2x2 waves, each 64x64 = 4x4 MFMA frags).
// Triple-buffered LDS (48KB), depth-2 counted-vmcnt pipeline (R7, best).
// XCD-rect swizzle: requires gridDim.x % 2 == 0, gridDim.y % 4 == 0.
template <int EPI>
__global__ void __launch_bounds__(256) gemm128(
    const unsigned short* __restrict__ A, const unsigned short* __restrict__ Bt,
    float* __restrict__ outF, unsigned short* __restrict__ qo,
    unsigned short* __restrict__ ko, unsigned short* __restrict__ vTo, int N) {
  __shared__ unsigned short la[3][4][128][8];
  __shared__ unsigned short lb[3][4][128][8];
  const int K = 1024;
  const int NT = K / 32;  // 32 K-tiles
  // XCD-rectangle swizzle: HW assigns XCD = orig % 8 (round-robin). Each
  // XCD x in (2 cols x 4 rows) layout owns a (gx/2 x gy/4) tile rectangle;
  // within-rect order is bx-fast (A-panel stays hot in its L2).
  int gx = gridDim.x, gy = gridDim.y;
  int orig = blockIdx.y * gx + blockIdx.x;
  int xcd = orig & 7, i = orig >> 3;
  int rw = gx >> 1, rh = gy >> 2;
  int bx = (xcd & 1) * rw + i % rw;
  int by = (xcd >> 1) * rh + i / rw;
  int mb = by * 128, nb = bx * 128;
  int tid = threadIdx.x;
  int l = tid & 63, w = tid >> 6;
  int wr = w >> 1, wc = w & 1;
  int lr = l & 15, lg = l >> 4;
  f32x4 acc[4][4] = {};
  int c0 = tid >> 7, r0 = tid & 127;

  auto STAGE = [&](int t, int buf) {
    int kb = t * 32;
    gload16(A + (size_t)(mb + r0) * K + kb + c0 * 8, &la[buf][c0][r0][0]);
    gload16(A + (size_t)(mb + r0) * K + kb + (c0 + 2) * 8, &la[buf][c0 + 2][r0][0]);
    gload16(Bt + (size_t)(nb + r0) * K + kb + c0 * 8, &lb[buf][c0][r0][0]);
    gload16(Bt + (size_t)(nb + r0) * K + kb + (c0 + 2) * 8, &lb[buf][c0 + 2][r0][0]);
  };
  auto COMPUTE = [&](int buf) {
    bf16x8 af[4], bfr[4];
#pragma unroll
    for (int mi = 0; mi < 4; mi++) af[mi] = ldfrag(&la[buf][lg][wr * 64 + mi * 16 + lr][0]);
#pragma unroll
    for (int ni = 0; ni < 4; ni++) bfr[ni] = ldfrag(&lb[buf][lg][wc * 64 + ni * 16 + lr][0]);
#pragma unroll
    for (int mi = 0; mi < 4; mi++)
#pragma unroll
      for (int ni = 0; ni < 4; ni++)
        acc[mi][ni] = __builtin_amdgcn_mfma_f32_16x16x32_bf16(af[mi], bfr[ni], acc[mi][ni], 0, 0, 0);
  };

  STAGE(0, 0);
  STAGE(1, 1);
  for (int i2 = 0; i2 < NT - 1; ++i2) {
    asm volatile("s_waitcnt vmcnt(4)" ::: "memory");
    __builtin_amdgcn_s_barrier();
    __builtin_amdgcn_sched_barrier(0);
    if (i2 + 2 < NT) STAGE(i2 + 2, (i2 + 2) % 3);
    COMPUTE(i2 % 3);
  }
  asm volatile("s_waitcnt vmcnt(0)" ::: "memory");
  __builtin_amdgcn_s_barrier();
  __builtin_amdgcn_sched_barrier(0);
  COMPUTE((NT - 1) % 3);

#pragma unroll
  for (int mi = 0; mi < 4; mi++) {
#pragma unroll
    for (int ni = 0; ni < 4; ni++) {
      int row0 = mb + wr * 64 + mi * 16 + lg * 4;
      int col = nb + wc * 64 + ni * 16 + lr;
      if (EPI == 1) {
#pragma unroll
        for (int r = 0; r < 4; r++)
          outF[(size_t)(row0 + r) * N + col] = acc[mi][ni][r];
      } else {
        int which = col >> 10, cc = col & 1023;
        int h = cc >> 6, d = cc & 63;
        int bb = row0 >> 11, t = row0 & 2047;
        size_t bh = (size_t)bb * Hv + h;
        if (which == 0) {
#pragma unroll
          for (int r = 0; r < 4; r++)
            qo[(bh * Tv + t + r) * Dv + d] = f2bs(acc[mi][ni][r]);
        } else if (which == 1) {
#pragma unroll
          for (int r = 0; r < 4; r++)
            ko[(bh * Tv + t + r) * Dv + d] = f2bs(acc[mi][ni][r]);
        } else {  // v stored transposed [B,H,D,T]
          ushort4v pk;
#pragma unroll
          for (int r = 0; r < 4; r++) pk[r] = f2bs(acc[mi][ni][r]);
          *reinterpret_cast<ushort4v*>(&vTo[(bh * Dv + d) * Tv + t]) = pk;
        }
      }
    }
  }
}

// ---------------- flash attention (R15: complementary static mapping) ------
// grid 512 blocks (1D), 512 threads = 8 waves; block covers 128 q-rows.
// p = idx&255, head = p&31, qh = 8+(p>>5); idx<256 -> qblk=qh (heavy),
// idx>=256 -> qblk=15-qh (light). Co-resident pair (c, c+256) sums to 34
// tiles on every CU. KT=64, dbuf K/V, one __syncthreads per tile. Per-wave
// causal mask/skip. Swapped QK^T; bf16-typed packed P-stores; ones-MFMA
// row-sum; defer-max. NOTE: the staged body must stay in this proven
// structure — straight-line single-tile variants miscompile (R10/R18).
__global__ void __launch_bounds__(512) flash_attn(
    const unsigned short* __restrict__ Q, const unsigned short* __restrict__ Kk,
    const unsigned short* __restrict__ Vt, unsigned short* __restrict__ O) {
  __shared__ unsigned short lK[2][8][64][8];  // 16KB
  __shared__ unsigned short lV[2][8][64][8];  // 16KB
  __shared__ __bf16 lP[8][16][72];            // 18KB, wave-private slabs
  int idx = blockIdx.x;
  int p = idx & 255;
  int bh = p & 31;
  int qh = 8 + (p >> 5);
  int qblk = (idx < 256) ? qh : (15 - qh);
  int b = bh >> 4, h = bh & 15;
  int tid = threadIdx.x;
  int l = tid & 63, w = tid >> 6;  // w = 0..7
  int lr = l & 15, lg = l >> 4;
  const unsigned short* Qp = Q + (size_t)bh * Tv * Dv;
  const unsigned short* Kp = Kk + (size_t)bh * Tv * Dv;
  const unsigned short* Vp = Vt + (size_t)bh * Dv * Tv;
  const float Cs = 0.125f * 1.4426950408889634f;  // scale * log2(e)
  const float THRraw = 8.0f / Cs;                 // defer-max threshold (P <= 2^8)
  const __bf16 kOne = (__bf16)1.0f;
  const bf16x8 vone = {kOne, kOne, kOne, kOne, kOne, kOne, kOne, kOne};
  int sr = l, sc = w;  // staging: wave w stages chunk w (1 K + 1 V gload16)

  int q0 = qblk * 128;
  int nt = 2 * qblk + 2;
  int qrow = q0 + w * 16 + lr;
  bf16x8 qf0 = ldfrag(&Qp[(size_t)qrow * Dv + lg * 8]);
  bf16x8 qf1 = ldfrag(&Qp[(size_t)qrow * Dv + 32 + lg * 8]);
  f32x4 o[4] = {};
  f32x4 lsum = {0.f, 0.f, 0.f, 0.f};  // rho-domain (row = lg*4+r)
  float mrow = -1e30f;                // lr-domain scalar (row = lr)
  int wlo = q0 + w * 16;              // wave's lowest q-row

  auto STAGE = [&](int it, int buf) {
    int k0 = it * 64;
    gload16(Kp + (size_t)(k0 + sr) * Dv + sc * 8, &lK[buf][sc][sr][0]);
    gload16(Vp + (size_t)sr * Tv + k0 + sc * 8, &lV[buf][sc][sr][0]);
  };

  STAGE(0, 0);
  int cur = 0;
  for (int it = 0; it < nt; ++it) {
    __syncthreads();  // drains prefetch of tile `it` + protects buffer reuse
    if (it + 1 < nt) STAGE(it + 1, cur ^ 1);
    int k0 = it * 64;
    if (k0 <= wlo + 15) {  // wave-uniform skip: tile intersects wave's rows
      // S^T = K Q^T : 4 row blocks of 16 keys; col=lr is the q-row.
      f32x4 s[4] = {};
#pragma unroll
      for (int j = 0; j < 4; ++j) {
        bf16x8 kf0 = ldfrag(&lK[cur][lg][j * 16 + lr][0]);
        s[j] = __builtin_amdgcn_mfma_f32_16x16x32_bf16(kf0, qf0, s[j], 0, 0, 0);
        bf16x8 kf1 = ldfrag(&lK[cur][4 + lg][j * 16 + lr][0]);
        s[j] = __builtin_amdgcn_mfma_f32_16x16x32_bf16(kf1, qf1, s[j], 0, 0, 0);
      }
      // lane (lg,lr) holds keys {k0+16j+4lg+r} for q-row lr
      int qg = wlo + lr;
      if (k0 + 63 > wlo) {  // diagonal straddle for this wave
#pragma unroll
        for (int j = 0; j < 4; ++j)
#pragma unroll
          for (int r = 0; r < 4; ++r)
            if (k0 + j * 16 + lg * 4 + r > qg) s[j][r] = -1e30f;
      }
      // tile max of q-row lr: 15 local fmax + 2 shuffles across lg
      float v = fmaxf(fmaxf(fmaxf(s[0][0], s[0][1]), fmaxf(s[0][2], s[0][3])),
                      fmaxf(fmaxf(s[1][0], s[1][1]), fmaxf(s[1][2], s[1][3])));
      v = fmaxf(v, fmaxf(fmaxf(fmaxf(s[2][0], s[2][1]), fmaxf(s[2][2], s[2][3])),
                         fmaxf(fmaxf(s[3][0], s[3][1]), fmaxf(s[3][2], s[3][3]))));
      v = fmaxf(v, __shfl_xor(v, 16));
      v = fmaxf(v, __shfl_xor(v, 32));
      // T13 defer-max: rescale only when this row's max grew past threshold
      if (__any(v > mrow + THRraw)) {
        float mn = fmaxf(mrow, v);
        float al = exp2f((mrow - mn) * Cs);  // lr-domain
        mrow = mn;
#pragma unroll
        for (int r = 0; r < 4; ++r) {  // cross to rho-domain (4 shfl, rare)
          float alr = __shfl(al, (l & 48) | (lg * 4 + r));
          lsum[r] *= alr;
#pragma unroll
          for (int nb = 0; nb < 4; ++nb) o[nb][r] *= alr;
        }
      }
      // P = exp2((S - m)*Cs), packed 4 consecutive keys -> one ds_write_b64
#pragma unroll
      for (int j = 0; j < 4; ++j) {
        bf16x4 pk;
#pragma unroll
        for (int r = 0; r < 4; ++r) pk[r] = (__bf16)exp2f((s[j][r] - mrow) * Cs);
        *reinterpret_cast<bf16x4*>(&lP[w][lr][j * 16 + lg * 4]) = pk;
      }
      asm volatile("" ::: "memory");  // fence: P stores before P reads
      // PV + row-sum: A = P (wave-private LDS), B = V^T tile / ones
      f32x4 srow = {0.f, 0.f, 0.f, 0.f};
#pragma unroll
      for (int kk = 0; kk < 2; ++kk) {
        bf16x8 pf = ldfragb(&lP[w][lr][kk * 32 + lg * 8]);
        srow = __builtin_amdgcn_mfma_f32_16x16x32_bf16(pf, vone, srow, 0, 0, 0);
#pragma unroll
        for (int nb = 0; nb < 4; ++nb) {
          bf16x8 vf = ldfrag(&lV[cur][kk * 4 + lg][nb * 16 + lr][0]);
          o[nb] = __builtin_amdgcn_mfma_f32_16x16x32_bf16(pf, vf, o[nb], 0, 0, 0);
        }
      }
      asm volatile("" ::: "memory");  // fence: P reads before next stores
#pragma unroll
      for (int r = 0; r < 4; ++r) lsum[r] += srow[r];
    }
    cur ^= 1;
  }
  // epilogue: normalize, write [B,T,H*D] bf16 (rho-domain rows)
#pragma unroll
  for (int r = 0; r < 4; ++r) {
    int t = q0 + w * 16 + lg * 4 + r;
    float inv = 1.0f / lsum[r];
    size_t rowbase = ((size_t)b * Tv + t) * Cv + h * Dv;
#pragma unroll
    for (int nb = 0; nb < 4; ++nb)
      O[rowbase + nb * 16 + lr] = f2bs(o[nb][r] * inv);
  }
}

// ---------------- host ----------------
extern "C" void kernel_launch(void* const* d_in, const int* in_sizes, int n_in,
                              void* d_out, int out_size, void* d_ws, size_t ws_size,
                              hipStream_t stream) {
  const float* x = (const float*)d_in[0];      // [2,2048,1024]
  const float* w_qkv = (const float*)d_in[1];  // [1024,3072]
  const float* w_out = (const float*)d_in[2];  // [1024,1024]
  float* out = (float*)d_out;                  // [2,2048,1024] f32
  char* ws = (char*)d_ws;
  const size_t MB = 1u << 20;
  unsigned short* xb    = (unsigned short*)(ws + 0);        // 8MB  [4096][1024]
  unsigned short* wqkvT = (unsigned short*)(ws + 8 * MB);   // 6MB  [3072][1024]
  unsigned short* woutT = (unsigned short*)(ws + 14 * MB);  // 2MB  [1024][1024]
  unsigned short* qb    = (unsigned short*)(ws + 16 * MB);  // 8MB  [B,H,T,D]
  unsigned short* kb    = (unsigned short*)(ws + 24 * MB);  // 8MB  [B,H,T,D]
  unsigned short* vTb   = (unsigned short*)(ws + 32 * MB);  // 8MB  [B,H,D,T]
  unsigned short* ab    = (unsigned short*)(ws + 40 * MB);  // 8MB  [4096][1024]

  prep_fused<<<dim3(2048 + 3072 + 1024), dim3(256), 0, stream>>>(
      x, xb, w_qkv, wqkvT, w_out, woutT);
  gemm128<0><<<dim3(3072 / 128, Mv / 128), dim3(256), 0, stream>>>(
      xb, wqkvT, nullptr, qb, kb, vTb, 3072);
  flash_attn<<<dim3(512), dim3(512), 0, stream>>>(qb, kb, vTb, ab);
  gemm128<1><<<dim3(Cv / 128, Mv / 128), dim3(256), 0, stream>>>(
      ab, woutT, out, nullptr, nullptr, nullptr, Cv);
}

// Round 21
// 129.363 us; speedup vs baseline: 1.0180x; 1.0010x over previous
//
#include <hip/hip_runtime.h>
#include <hip/hip_bf16.h>
#include <stdint.h>

// B=2, T=2048, C=1024, H=16, D=64
// out = ( causal_attn(x@Wqkv) ) @ Wout
// bf16 MFMA pipeline, f32 accumulate everywhere.
// R21: confirmation of R20 (session best, 129.5us) — byte-identical.
//  - prep_fused: x-cast + both weight transposes, one launch (~6us, BW floor)
//  - gemm128: 128^2/BK=32, triple-buffered, depth-2 counted-vmcnt, XCD-rect
//    swizzle (FETCH 39.5->33.2MB; dur flat => convoy-bound, closed)
//  - flash: R15 complementary static mapping (512x8-wave, 34 tiles/CU
//    exactly), pairing-structure body (straight-line staged bodies
//    miscompile — R10/R18), TBAA-typed lP, swapped QK^T, ones-MFMA row-sum,
//    defer-max.
// Plateau: all pipes <26% busy; 5 qkv schedule variants within ±1us.

#define Bv 2
#define Tv 2048
#define Cv 1024
#define Hv 16
#define Dv 64
#define Mv 4096  // B*T

typedef __attribute__((ext_vector_type(8))) __bf16 bf16x8;
typedef __attribute__((ext_vector_type(4))) __bf16 bf16x4;
typedef __attribute__((ext_vector_type(4))) float f32x4;
typedef __attribute__((ext_vector_type(4))) unsigned short ushort4v;

__device__ __forceinline__ unsigned short f2bs(float f) {
  union { __bf16 h; unsigned short s; } u;
  u.h = (__bf16)f;  // native HW cvt (RNE on gfx950)
  return u.s;
}

__device__ __forceinline__ void gload16(const void* g, void* l) {
  __builtin_amdgcn_global_load_lds(
      (__attribute__((address_space(1))) void*)(uintptr_t)g,
      (__attribute__((address_space(3))) void*)(unsigned int)(uintptr_t)l,
      16, 0, 0);
}

__device__ __forceinline__ bf16x8 ldfrag(const unsigned short* p) {
  return *reinterpret_cast<const bf16x8*>(p);
}
__device__ __forceinline__ bf16x8 ldfragb(const __bf16* p) {
  return *reinterpret_cast<const bf16x8*>(p);
}

// ---------------- fused prep: x cast + w_qkv transpose + w_out transpose ---
// blocks [0,2048): cast x f32->bf16, 8 elems/thread.
// blocks [2048,5120): transpose+cast w_qkv [1024][3072] -> wqkvT [3072][1024]
// blocks [5120,6144): transpose+cast w_out [1024][1024] -> woutT [1024][1024]
__global__ void __launch_bounds__(256) prep_fused(
    const float* __restrict__ x, unsigned short* __restrict__ xb,
    const float* __restrict__ w_qkv, unsigned short* __restrict__ wqkvT,
    const float* __restrict__ w_out, unsigned short* __restrict__ woutT) {
  __shared__ float tile[32][33];
  int idx = blockIdx.x;
  if (idx < 2048) {  // cast role
    int i = (idx * 256 + threadIdx.x) * 8;
    float4 a = *reinterpret_cast<const float4*>(x + i);
    float4 b = *reinterpret_cast<const float4*>(x + i + 4);
    ushort4v o0, o1;
    o0.x = f2bs(a.x); o0.y = f2bs(a.y); o0.z = f2bs(a.z); o0.w = f2bs(a.w);
    o1.x = f2bs(b.x); o1.y = f2bs(b.y); o1.z = f2bs(b.z); o1.w = f2bs(b.w);
    *reinterpret_cast<ushort4v*>(xb + i) = o0;
    *reinterpret_cast<ushort4v*>(xb + i + 4) = o1;
    return;
  }
  // transpose roles: in f32 [1024][Cc] -> out bf16 [Cc][1024]
  const float* in;
  unsigned short* out;
  int Cc, bx, by;
  if (idx < 5120) {
    int t = idx - 2048;
    in = w_qkv; out = wqkvT; Cc = 3072; bx = t % 96; by = t / 96;
  } else {
    int t = idx - 5120;
    in = w_out; out = woutT; Cc = 1024; bx = t & 31; by = t >> 5;
  }
  const int R = 1024;
  int c0 = bx * 32, r0 = by * 32;
  int tc = threadIdx.x & 31, tr = threadIdx.x >> 5;
#pragma unroll
  for (int i = 0; i < 4; i++)
    tile[tr + i * 8][tc] = in[(size_t)(r0 + tr + i * 8) * Cc + c0 + tc];
  __syncthreads();
#pragma unroll
  for (int i = 0; i < 4; i++)
    out[(size_t)(c0 + tr + i * 8) * R + r0 + tc] = f2bs(tile[tc][tr + i * 8]);
}

// ---------------- GEMM: C[M][N] = A[M][1024] * Bt[N][1024]^T ----------------
// 128x128 tile, BK=32, 256 threads (2x2 waves, each 64x64 = 4x4 MFMA frags).
// Triple-buffered LDS (48KB), depth-2 counted-vmcnt pipeline (R7, best).
// XCD-rect swizzle: requires gridDim.x % 2 == 0, gridDim.y % 4 == 0.
template <int EPI>
__global__ void __launch_bounds__(256) gemm128(
    const unsigned short* __restrict__ A, const unsigned short* __restrict__ Bt,
    float* __restrict__ outF, unsigned short* __restrict__ qo,
    unsigned short* __restrict__ ko, unsigned short* __restrict__ vTo, int N) {
  __shared__ unsigned short la[3][4][128][8];
  __shared__ unsigned short lb[3][4][128][8];
  const int K = 1024;
  const int NT = K / 32;  // 32 K-tiles
  // XCD-rectangle swizzle: HW assigns XCD = orig % 8 (round-robin). Each
  // XCD x in (2 cols x 4 rows) layout owns a (gx/2 x gy/4) tile rectangle;
  // within-rect order is bx-fast (A-panel stays hot in its L2).
  int gx = gridDim.x, gy = gridDim.y;
  int orig = blockIdx.y * gx + blockIdx.x;
  int xcd = orig & 7, i = orig >> 3;
  int rw = gx >> 1, rh = gy >> 2;
  int bx = (xcd & 1) * rw + i % rw;
  int by = (xcd >> 1) * rh + i / rw;
  int mb = by * 128, nb = bx * 128;
  int tid = threadIdx.x;
  int l = tid & 63, w = tid >> 6;
  int wr = w >> 1, wc = w & 1;
  int lr = l & 15, lg = l >> 4;
  f32x4 acc[4][4] = {};
  int c0 = tid >> 7, r0 = tid & 127;

  auto STAGE = [&](int t, int buf) {
    int kb = t * 32;
    gload16(A + (size_t)(mb + r0) * K + kb + c0 * 8, &la[buf][c0][r0][0]);
    gload16(A + (size_t)(mb + r0) * K + kb + (c0 + 2) * 8, &la[buf][c0 + 2][r0][0]);
    gload16(Bt + (size_t)(nb + r0) * K + kb + c0 * 8, &lb[buf][c0][r0][0]);
    gload16(Bt + (size_t)(nb + r0) * K + kb + (c0 + 2) * 8, &lb[buf][c0 + 2][r0][0]);
  };
  auto COMPUTE = [&](int buf) {
    bf16x8 af[4], bfr[4];
#pragma unroll
    for (int mi = 0; mi < 4; mi++) af[mi] = ldfrag(&la[buf][lg][wr * 64 + mi * 16 + lr][0]);
#pragma unroll
    for (int ni = 0; ni < 4; ni++) bfr[ni] = ldfrag(&lb[buf][lg][wc * 64 + ni * 16 + lr][0]);
#pragma unroll
    for (int mi = 0; mi < 4; mi++)
#pragma unroll
      for (int ni = 0; ni < 4; ni++)
        acc[mi][ni] = __builtin_amdgcn_mfma_f32_16x16x32_bf16(af[mi], bfr[ni], acc[mi][ni], 0, 0, 0);
  };

  STAGE(0, 0);
  STAGE(1, 1);
  for (int i2 = 0; i2 < NT - 1; ++i2) {
    asm volatile("s_waitcnt vmcnt(4)" ::: "memory");
    __builtin_amdgcn_s_barrier();
    __builtin_amdgcn_sched_barrier(0);
    if (i2 + 2 < NT) STAGE(i2 + 2, (i2 + 2) % 3);
    COMPUTE(i2 % 3);
  }
  asm volatile("s_waitcnt vmcnt(0)" ::: "memory");
  __builtin_amdgcn_s_barrier();
  __builtin_amdgcn_sched_barrier(0);
  COMPUTE((NT - 1) % 3);

#pragma unroll
  for (int mi = 0; mi < 4; mi++) {
#pragma unroll
    for (int ni = 0; ni < 4; ni++) {
      int row0 = mb + wr * 64 + mi * 16 + lg * 4;
      int col = nb + wc * 64 + ni * 16 + lr;
      if (EPI == 1) {
#pragma unroll
        for (int r = 0; r < 4; r++)
          outF[(size_t)(row0 + r) * N + col] = acc[mi][ni][r];
      } else {
        int which = col >> 10, cc = col & 1023;
        int h = cc >> 6, d = cc & 63;
        int bb = row0 >> 11, t = row0 & 2047;
        size_t bh = (size_t)bb * Hv + h;
        if (which == 0) {
#pragma unroll
          for (int r = 0; r < 4; r++)
            qo[(bh * Tv + t + r) * Dv + d] = f2bs(acc[mi][ni][r]);
        } else if (which == 1) {
#pragma unroll
          for (int r = 0; r < 4; r++)
            ko[(bh * Tv + t + r) * Dv + d] = f2bs(acc[mi][ni][r]);
        } else {  // v stored transposed [B,H,D,T]
          ushort4v pk;
#pragma unroll
          for (int r = 0; r < 4; r++) pk[r] = f2bs(acc[mi][ni][r]);
          *reinterpret_cast<ushort4v*>(&vTo[(bh * Dv + d) * Tv + t]) = pk;
        }
      }
    }
  }
}

// ---------------- flash attention (R15: complementary static mapping) ------
// grid 512 blocks (1D), 512 threads = 8 waves; block covers 128 q-rows.
// p = idx&255, head = p&31, qh = 8+(p>>5); idx<256 -> qblk=qh (heavy),
// idx>=256 -> qblk=15-qh (light). Co-resident pair (c, c+256) sums to 34
// tiles on every CU. KT=64, dbuf K/V, one __syncthreads per tile. Per-wave
// causal mask/skip. Swapped QK^T; bf16-typed packed P-stores; ones-MFMA
// row-sum; defer-max. NOTE: the staged body must stay in this proven
// structure — straight-line single-tile variants miscompile (R10/R18).
__global__ void __launch_bounds__(512) flash_attn(
    const unsigned short* __restrict__ Q, const unsigned short* __restrict__ Kk,
    const unsigned short* __restrict__ Vt, unsigned short* __restrict__ O) {
  __shared__ unsigned short lK[2][8][64][8];  // 16KB
  __shared__ unsigned short lV[2][8][64][8];  // 16KB
  __shared__ __bf16 lP[8][16][72];            // 18KB, wave-private slabs
  int idx = blockIdx.x;
  int p = idx & 255;
  int bh = p & 31;
  int qh = 8 + (p >> 5);
  int qblk = (idx < 256) ? qh : (15 - qh);
  int b = bh >> 4, h = bh & 15;
  int tid = threadIdx.x;
  int l = tid & 63, w = tid >> 6;  // w = 0..7
  int lr = l & 15, lg = l >> 4;
  const unsigned short* Qp = Q + (size_t)bh * Tv * Dv;
  const unsigned short* Kp = Kk + (size_t)bh * Tv * Dv;
  const unsigned short* Vp = Vt + (size_t)bh * Dv * Tv;
  const float Cs = 0.125f * 1.4426950408889634f;  // scale * log2(e)
  const float THRraw = 8.0f / Cs;                 // defer-max threshold (P <= 2^8)
  const __bf16 kOne = (__bf16)1.0f;
  const bf16x8 vone = {kOne, kOne, kOne, kOne, kOne, kOne, kOne, kOne};
  int sr = l, sc = w;  // staging: wave w stages chunk w (1 K + 1 V gload16)

  int q0 = qblk * 128;
  int nt = 2 * qblk + 2;
  int qrow = q0 + w * 16 + lr;
  bf16x8 qf0 = ldfrag(&Qp[(size_t)qrow * Dv + lg * 8]);
  bf16x8 qf1 = ldfrag(&Qp[(size_t)qrow * Dv + 32 + lg * 8]);
  f32x4 o[4] = {};
  f32x4 lsum = {0.f, 0.f, 0.f, 0.f};  // rho-domain (row = lg*4+r)
  float mrow = -1e30f;                // lr-domain scalar (row = lr)
  int wlo = q0 + w * 16;              // wave's lowest q-row

  auto STAGE = [&](int it, int buf) {
    int k0 = it * 64;
    gload16(Kp + (size_t)(k0 + sr) * Dv + sc * 8, &lK[buf][sc][sr][0]);
    gload16(Vp + (size_t)sr * Tv + k0 + sc * 8, &lV[buf][sc][sr][0]);
  };

  STAGE(0, 0);
  int cur = 0;
  for (int it = 0; it < nt; ++it) {
    __syncthreads();  // drains prefetch of tile `it` + protects buffer reuse
    if (it + 1 < nt) STAGE(it + 1, cur ^ 1);
    int k0 = it * 64;
    if (k0 <= wlo + 15) {  // wave-uniform skip: tile intersects wave's rows
      // S^T = K Q^T : 4 row blocks of 16 keys; col=lr is the q-row.
      f32x4 s[4] = {};
#pragma unroll
      for (int j = 0; j < 4; ++j) {
        bf16x8 kf0 = ldfrag(&lK[cur][lg][j * 16 + lr][0]);
        s[j] = __builtin_amdgcn_mfma_f32_16x16x32_bf16(kf0, qf0, s[j], 0, 0, 0);
        bf16x8 kf1 = ldfrag(&lK[cur][4 + lg][j * 16 + lr][0]);
        s[j] = __builtin_amdgcn_mfma_f32_16x16x32_bf16(kf1, qf1, s[j], 0, 0, 0);
      }
      // lane (lg,lr) holds keys {k0+16j+4lg+r} for q-row lr
      int qg = wlo + lr;
      if (k0 + 63 > wlo) {  // diagonal straddle for this wave
#pragma unroll
        for (int j = 0; j < 4; ++j)
#pragma unroll
          for (int r = 0; r < 4; ++r)
            if (k0 + j * 16 + lg * 4 + r > qg) s[j][r] = -1e30f;
      }
      // tile max of q-row lr: 15 local fmax + 2 shuffles across lg
      float v = fmaxf(fmaxf(fmaxf(s[0][0], s[0][1]), fmaxf(s[0][2], s[0][3])),
                      fmaxf(fmaxf(s[1][0], s[1][1]), fmaxf(s[1][2], s[1][3])));
      v = fmaxf(v, fmaxf(fmaxf(fmaxf(s[2][0], s[2][1]), fmaxf(s[2][2], s[2][3])),
                         fmaxf(fmaxf(s[3][0], s[3][1]), fmaxf(s[3][2], s[3][3]))));
      v = fmaxf(v, __shfl_xor(v, 16));
      v = fmaxf(v, __shfl_xor(v, 32));
      // T13 defer-max: rescale only when this row's max grew past threshold
      if (__any(v > mrow + THRraw)) {
        float mn = fmaxf(mrow, v);
        float al = exp2f((mrow - mn) * Cs);  // lr-domain
        mrow = mn;
#pragma unroll
        for (int r = 0; r < 4; ++r) {  // cross to rho-domain (4 shfl, rare)
          float alr = __shfl(al, (l & 48) | (lg * 4 + r));
          lsum[r] *= alr;
#pragma unroll
          for (int nb = 0; nb < 4; ++nb) o[nb][r] *= alr;
        }
      }
      // P = exp2((S - m)*Cs), packed 4 consecutive keys -> one ds_write_b64
#pragma unroll
      for (int j = 0; j < 4; ++j) {
        bf16x4 pk;
#pragma unroll
        for (int r = 0; r < 4; ++r) pk[r] = (__bf16)exp2f((s[j][r] - mrow) * Cs);
        *reinterpret_cast<bf16x4*>(&lP[w][lr][j * 16 + lg * 4]) = pk;
      }
      asm volatile("" ::: "memory");  // fence: P stores before P reads
      // PV + row-sum: A = P (wave-private LDS), B = V^T tile / ones
      f32x4 srow = {0.f, 0.f, 0.f, 0.f};
#pragma unroll
      for (int kk = 0; kk < 2; ++kk) {
        bf16x8 pf = ldfragb(&lP[w][lr][kk * 32 + lg * 8]);
        srow = __builtin_amdgcn_mfma_f32_16x16x32_bf16(pf, vone, srow, 0, 0, 0);
#pragma unroll
        for (int nb = 0; nb < 4; ++nb) {
          bf16x8 vf = ldfrag(&lV[cur][kk * 4 + lg][nb * 16 + lr][0]);
          o[nb] = __builtin_amdgcn_mfma_f32_16x16x32_bf16(pf, vf, o[nb], 0, 0, 0);
        }
      }
      asm volatile("" ::: "memory");  // fence: P reads before next stores
#pragma unroll
      for (int r = 0; r < 4; ++r) lsum[r] += srow[r];
    }
    cur ^= 1;
  }
  // epilogue: normalize, write [B,T,H*D] bf16 (rho-domain rows)
#pragma unroll
  for (int r = 0; r < 4; ++r) {
    int t = q0 + w * 16 + lg * 4 + r;
    float inv = 1.0f / lsum[r];
    size_t rowbase = ((size_t)b * Tv + t) * Cv + h * Dv;
#pragma unroll
    for (int nb = 0; nb < 4; ++nb)
      O[rowbase + nb * 16 + lr] = f2bs(o[nb][r] * inv);
  }
}

// ---------------- host ----------------
extern "C" void kernel_launch(void* const* d_in, const int* in_sizes, int n_in,
                              void* d_out, int out_size, void* d_ws, size_t ws_size,
                              hipStream_t stream) {
  const float* x = (const float*)d_in[0];      // [2,2048,1024]
  const float* w_qkv = (const float*)d_in[1];  // [1024,3072]
  const float* w_out = (const float*)d_in[2];  // [1024,1024]
  float* out = (float*)d_out;                  // [2,2048,1024] f32
  char* ws = (char*)d_ws;
  const size_t MB = 1u << 20;
  unsigned short* xb    = (unsigned short*)(ws + 0);        // 8MB  [4096][1024]
  unsigned short* wqkvT = (unsigned short*)(ws + 8 * MB);   // 6MB  [3072][1024]
  unsigned short* woutT = (unsigned short*)(ws + 14 * MB);  // 2MB  [1024][1024]
  unsigned short* qb    = (unsigned short*)(ws + 16 * MB);  // 8MB  [B,H,T,D]
  unsigned short* kb    = (unsigned short*)(ws + 24 * MB);  // 8MB  [B,H,T,D]
  unsigned short* vTb   = (unsigned short*)(ws + 32 * MB);  // 8MB  [B,H,D,T]
  unsigned short* ab    = (unsigned short*)(ws + 40 * MB);  // 8MB  [4096][1024]

  prep_fused<<<dim3(2048 + 3072 + 1024), dim3(256), 0, stream>>>(
      x, xb, w_qkv, wqkvT, w_out, woutT);
  gemm128<0><<<dim3(3072 / 128, Mv / 128), dim3(256), 0, stream>>>(
      xb, wqkvT, nullptr, qb, kb, vTb, 3072);
  flash_attn<<<dim3(512), dim3(512), 0, stream>>>(qb, kb, vTb, ab);
  gemm128<1><<<dim3(Cv / 128, Mv / 128), dim3(256), 0, stream>>>(
      ab, woutT, out, nullptr, nullptr, nullptr, Cv);
}